// Round 2
// baseline (577.588 us; speedup 1.0000x reference)
//
#include <hip/hip_runtime.h>

#define S_LEN 1024
#define DH    64
#define KVBLK 64
#define NCH   (S_LEN / KVBLK)      // 16
#define WAVES 8
#define BLOCK (WAVES * 64)          // 512
#define QT    (WAVES * 32)          // 256 q-rows per block
#define OUT_ELEMS (4 * 16 * 1024 * 64)

typedef _Float16 f16x8  __attribute__((ext_vector_type(8)));
typedef float    f32x4  __attribute__((ext_vector_type(4)));
typedef float    f32x16 __attribute__((ext_vector_type(16)));

__device__ __forceinline__ unsigned pk2(float a, float b) {
    union { _Float16 h[2]; unsigned u; } x;
    x.h[0] = (_Float16)a; x.h[1] = (_Float16)b; return x.u;
}

__global__ __launch_bounds__(BLOCK, 1)
void attn_fused(const float* __restrict__ qg, const float* __restrict__ kg,
                const float* __restrict__ vg, float* __restrict__ dout)
{
    // 256 blocks; bijective XCD swizzle keeps a head's 4 q-tiles on one XCD (L2 reuse of K/V)
    const int bid = blockIdx.x;
    const int nb  = (bid & 7) * 32 + (bid >> 3);
    const int bh  = nb >> 2;          // head 0..63
    const int qt  = nb & 3;           // q-tile 0..3
    const int qbase = qt * QT;

    const float* __restrict__ qh = qg + (size_t)bh * S_LEN * DH;
    const float* __restrict__ kh = kg + (size_t)bh * S_LEN * DH;
    const float* __restrict__ vh = vg + (size_t)bh * S_LEN * DH;
    float* __restrict__ outh  = dout + (size_t)bh * S_LEN * DH;
    float* __restrict__ attnh = dout + (size_t)OUT_ELEMS + (size_t)bh * S_LEN * S_LEN;

    // K: [krow][d ^ ((krow&7)<<3)]   V^T: [d][vr ^ ((d&7)<<3)]   (XOR-swizzle, G4)
    __shared__ _Float16 kbuf[2][KVBLK * DH];   // 16 KB
    __shared__ _Float16 vbuf[2][DH * KVBLK];   // 16 KB

    const int tid = threadIdx.x;
    const int w   = tid >> 6;
    const int l   = tid & 63;
    const int qr  = l & 31;           // this lane's q-row (within wave tile) AND d-col for PV-B
    const int hi  = l >> 5;
    const int q0w = qbase + w * 32;

    const int srow = tid >> 3;        // K staging: row 0..63
    const int sd0  = (tid & 7) * 8;   // K staging: 8-col chunk
    const int vd   = tid & 63;        // V staging: d column
    const int vr0  = (tid >> 6) * 8;  // V staging: 8 consecutive k-rows

    const float cexp = 0.18033688011112042f;   // log2(e)/8 — softmax scale fused into exp2

    // ---- Q B-fragments (col=lane&31=q, k = 16m + 8hi + e)
    f16x8 qf[4];
    {
        const float* qrow = qh + (size_t)(q0w + qr) * DH;
        #pragma unroll
        for (int m = 0; m < 4; ++m) {
            f32x4 a = *(const f32x4*)(qrow + m*16 + hi*8);
            f32x4 b = *(const f32x4*)(qrow + m*16 + hi*8 + 4);
            f16x8 f;
            #pragma unroll
            for (int j = 0; j < 4; ++j) { f[j] = (_Float16)a[j]; f[j+4] = (_Float16)b[j]; }
            qf[m] = f;
        }
    }

    f32x4 ka, kb;
    float vs[8];

    // ================= Pass 1: QK^T -> row sums (no stores) =================
    {
        const float* p = kh + (size_t)srow * DH + sd0;
        ka = *(const f32x4*)p; kb = *(const f32x4*)(p + 4);
        f16x8 f;
        #pragma unroll
        for (int j = 0; j < 4; ++j) { f[j] = (_Float16)ka[j]; f[j+4] = (_Float16)kb[j]; }
        *(f16x8*)&kbuf[0][srow*DH + (sd0 ^ ((srow & 7) << 3))] = f;
    }
    __syncthreads();

    float ssum = 0.f;
    for (int c = 0; c < NCH; ++c) {
        if (c + 1 < NCH) {   // issue-early
            const float* p = kh + (size_t)((c+1)*KVBLK + srow) * DH + sd0;
            ka = *(const f32x4*)p; kb = *(const f32x4*)(p + 4);
        }
        #pragma unroll
        for (int t = 0; t < 2; ++t) {
            const int kr  = t*32 + qr;
            const int swz = (kr & 7) << 3;
            f32x16 acc;
            #pragma unroll
            for (int r = 0; r < 16; ++r) acc[r] = 0.f;
            #pragma unroll
            for (int m = 0; m < 4; ++m) {
                f16x8 af = *(const f16x8*)&kbuf[c & 1][kr*DH + ((m*16 + hi*8) ^ swz)];
                acc = __builtin_amdgcn_mfma_f32_32x32x16_f16(af, qf[m], acc, 0, 0, 0);
            }
            #pragma unroll
            for (int r = 0; r < 16; ++r) ssum += __builtin_amdgcn_exp2f(acc[r] * cexp);
        }
        if (c + 1 < NCH) {   // write-late
            f16x8 f;
            #pragma unroll
            for (int j = 0; j < 4; ++j) { f[j] = (_Float16)ka[j]; f[j+4] = (_Float16)kb[j]; }
            *(f16x8*)&kbuf[(c+1) & 1][srow*DH + (sd0 ^ ((srow & 7) << 3))] = f;
        }
        __syncthreads();
    }

    // full row sum: lanes l and l^32 hold complementary halves of the same q-row
    ssum += __shfl_xor(ssum, 32);
    const float inv = 1.f / ssum;

    // ================= Pass 2: QK^T -> normalize -> store attn + PV =================
    {
        const float* p = kh + (size_t)srow * DH + sd0;
        ka = *(const f32x4*)p; kb = *(const f32x4*)(p + 4);
        #pragma unroll
        for (int j = 0; j < 8; ++j) vs[j] = vh[(size_t)(vr0 + j) * DH + vd];
        f16x8 f;
        #pragma unroll
        for (int j = 0; j < 4; ++j) { f[j] = (_Float16)ka[j]; f[j+4] = (_Float16)kb[j]; }
        *(f16x8*)&kbuf[0][srow*DH + (sd0 ^ ((srow & 7) << 3))] = f;
        f16x8 fv;
        #pragma unroll
        for (int j = 0; j < 8; ++j) fv[j] = (_Float16)vs[j];
        *(f16x8*)&vbuf[0][vd*KVBLK + (vr0 ^ ((vd & 7) << 3))] = fv;
    }
    __syncthreads();

    f32x16 oacc0, oacc1;
    #pragma unroll
    for (int r = 0; r < 16; ++r) { oacc0[r] = 0.f; oacc1[r] = 0.f; }

    float* arow = attnh + (size_t)(q0w + qr) * S_LEN;

    for (int c = 0; c < NCH; ++c) {
        if (c + 1 < NCH) {
            const float* p = kh + (size_t)((c+1)*KVBLK + srow) * DH + sd0;
            ka = *(const f32x4*)p; kb = *(const f32x4*)(p + 4);
            #pragma unroll
            for (int j = 0; j < 8; ++j) vs[j] = vh[(size_t)((c+1)*KVBLK + vr0 + j) * DH + vd];
        }
        const int cur = c & 1;
        #pragma unroll
        for (int t = 0; t < 2; ++t) {
            const int kr  = t*32 + qr;
            const int swz = (kr & 7) << 3;
            f32x16 acc;
            #pragma unroll
            for (int r = 0; r < 16; ++r) acc[r] = 0.f;
            #pragma unroll
            for (int m = 0; m < 4; ++m) {
                f16x8 af = *(const f16x8*)&kbuf[cur][kr*DH + ((m*16 + hi*8) ^ swz)];
                acc = __builtin_amdgcn_mfma_f32_32x32x16_f16(af, qf[m], acc, 0, 0, 0);
            }
            // normalized P for this lane's q-row; k_local(tile) = (r&3) + 8*(r>>2) + 4*hi
            float pn[16];
            #pragma unroll
            for (int r = 0; r < 16; ++r) pn[r] = __builtin_amdgcn_exp2f(acc[r] * cexp) * inv;
            // attn stores: contiguous quads at k = 32t + 8g + 4hi (nontemporal: never re-read)
            #pragma unroll
            for (int g = 0; g < 4; ++g) {
                f32x4 st; st[0]=pn[4*g]; st[1]=pn[4*g+1]; st[2]=pn[4*g+2]; st[3]=pn[4*g+3];
                __builtin_nontemporal_store(st, (f32x4*)&arow[c*64 + t*32 + g*8 + hi*4]);
            }
            // P -> fp16 A-fragments via pack + cross-half exchange (T12, convention-safe)
            unsigned wd[8], pw[8];
            #pragma unroll
            for (int i = 0; i < 8; ++i) wd[i] = pk2(pn[2*i], pn[2*i+1]);
            #pragma unroll
            for (int i = 0; i < 8; ++i) pw[i] = __shfl_xor(wd[i], 32);
            #pragma unroll
            for (int u = 0; u < 2; ++u) {
                union { unsigned u4[4]; f16x8 v; } af;
                af.u4[0] = hi ? pw[4*u+2] : wd[4*u+0];
                af.u4[1] = hi ? pw[4*u+3] : wd[4*u+1];
                af.u4[2] = hi ? wd[4*u+2] : pw[4*u+0];
                af.u4[3] = hi ? wd[4*u+3] : pw[4*u+1];
                const int s = 2*t + u;                 // k-slice of this chunk
                const int vswz = (qr & 7) << 3;
                f16x8 b0 = *(const f16x8*)&vbuf[cur][qr*KVBLK        + ((s*16 + hi*8) ^ vswz)];
                f16x8 b1 = *(const f16x8*)&vbuf[cur][(32+qr)*KVBLK   + ((s*16 + hi*8) ^ vswz)];
                oacc0 = __builtin_amdgcn_mfma_f32_32x32x16_f16(af.v, b0, oacc0, 0, 0, 0);
                oacc1 = __builtin_amdgcn_mfma_f32_32x32x16_f16(af.v, b1, oacc1, 0, 0, 0);
            }
        }
        if (c + 1 < NCH) {
            f16x8 f;
            #pragma unroll
            for (int j = 0; j < 4; ++j) { f[j] = (_Float16)ka[j]; f[j+4] = (_Float16)kb[j]; }
            *(f16x8*)&kbuf[(c+1) & 1][srow*DH + (sd0 ^ ((srow & 7) << 3))] = f;
            f16x8 fv;
            #pragma unroll
            for (int j = 0; j < 8; ++j) fv[j] = (_Float16)vs[j];
            *(f16x8*)&vbuf[(c+1) & 1][vd*KVBLK + (vr0 ^ ((vd & 7) << 3))] = fv;
        }
        __syncthreads();
    }

    // ================= Epilogue: O (already normalized — A was normalized P) =================
    #pragma unroll
    for (int od = 0; od < 2; ++od) {
        #pragma unroll
        for (int r = 0; r < 16; ++r) {
            const int qrow = (r & 3) + 8*(r >> 2) + 4*hi;
            const float val = od ? oacc1[r] : oacc0[r];
            __builtin_nontemporal_store(val, &outh[(size_t)(q0w + qrow) * DH + od*32 + qr]);
        }
    }
}

extern "C" void kernel_launch(void* const* d_in, const int* in_sizes, int n_in,
                              void* d_out, int out_size, void* d_ws, size_t ws_size,
                              hipStream_t stream) {
    const float* q = (const float*)d_in[0];
    const float* k = (const float*)d_in[1];
    const float* v = (const float*)d_in[2];
    float* out = (float*)d_out;
    attn_fused<<<dim3(256), dim3(BLOCK), 0, stream>>>(q, k, v, out);
}

// Round 4
// 465.130 us; speedup vs baseline: 1.2418x; 1.2418x over previous
//
#include <hip/hip_runtime.h>

#define S_LEN  1024
#define DH     64
#define CH     32                  // kv rows per chunk
#define NCHUNK (S_LEN / CH)        // 32
#define OUT_ELEMS (4 * 16 * 1024 * 64)

typedef _Float16 f16x8  __attribute__((ext_vector_type(8)));
typedef float    f32x4  __attribute__((ext_vector_type(4)));
typedef float    f32x16 __attribute__((ext_vector_type(16)));

__device__ __forceinline__ unsigned pk2(float a, float b) {
    union { _Float16 h[2]; unsigned u; } x;
    x.h[0] = (_Float16)a; x.h[1] = (_Float16)b; return x.u;
}

__global__ __launch_bounds__(256, 2)
void attn_fused(const float* __restrict__ qg, const float* __restrict__ kg,
                const float* __restrict__ vg, float* __restrict__ dout)
{
    // 512 blocks = 64 heads x 8 q-blocks. bid%8 == head%8 -> all of a head's
    // blocks land on one XCD (8 heads/XCD, K+V working set = 4 MB = L2).
    const int bid = blockIdx.x;
    const int h   = bid & 63;
    const int qb  = bid >> 6;
    const int tid = threadIdx.x;
    const int w   = tid >> 6;          // wave 0..3 (fully independent; NO barriers)
    const int l   = tid & 63;
    const int qr  = l & 31;            // q-row within strip / B-col / d-col
    const int hi  = l >> 5;
    const int q0  = qb * 128 + w * 32; // this wave's 32-row q-strip

    const float* __restrict__ qh = qg + (size_t)h * S_LEN * DH;
    const float* __restrict__ kh = kg + (size_t)h * S_LEN * DH;
    const float* __restrict__ vh = vg + (size_t)h * S_LEN * DH;
    float* __restrict__ outh  = dout + (size_t)h * S_LEN * DH;
    float* __restrict__ attnh = dout + (size_t)OUT_ELEMS + (size_t)h * S_LEN * S_LEN;

    // wave-private P transpose buffer: 32x32 f32, XOR group-swizzle (4-float granules)
    __shared__ float pstage[4][CH * CH];
    float* ps = pstage[w];

    const float cexp = 0.18033688011112042f;   // log2(e)/8 — softmax scale fused into exp2

    // ---- Q B-fragments (col=lane&31=q-row, k = 16m + 8hi + j)
    f16x8 qf[4];
    {
        const float* qrow = qh + (size_t)(q0 + qr) * DH + hi * 8;
        #pragma unroll
        for (int m = 0; m < 4; ++m) {
            f32x4 a = *(const f32x4*)(qrow + m*16);
            f32x4 b = *(const f32x4*)(qrow + m*16 + 4);
            f16x8 f;
            #pragma unroll
            for (int j = 0; j < 4; ++j) { f[j] = (_Float16)a[j]; f[j+4] = (_Float16)b[j]; }
            qf[m] = f;
        }
    }

    f32x4 ra[4], rb[4];    // next-chunk K raw (register double-buffer)
    f16x8 kf[4];           // current-chunk K A-fragments

    // ================= Pass 1: QK^T -> row sums =================
    {
        const float* kp = kh + (size_t)qr * DH + hi * 8;
        #pragma unroll
        for (int m = 0; m < 4; ++m) { ra[m] = *(const f32x4*)(kp + m*16); rb[m] = *(const f32x4*)(kp + m*16 + 4); }
        #pragma unroll
        for (int m = 0; m < 4; ++m) {
            f16x8 f;
            #pragma unroll
            for (int j = 0; j < 4; ++j) { f[j] = (_Float16)ra[m][j]; f[j+4] = (_Float16)rb[m][j]; }
            kf[m] = f;
        }
    }
    float ssum = 0.f;
    for (int c = 0; c < NCHUNK; ++c) {
        if (c + 1 < NCHUNK) {   // prefetch next K chunk into regs
            const float* kp = kh + (size_t)((c+1)*CH + qr) * DH + hi * 8;
            #pragma unroll
            for (int m = 0; m < 4; ++m) { ra[m] = *(const f32x4*)(kp + m*16); rb[m] = *(const f32x4*)(kp + m*16 + 4); }
        }
        f32x16 acc;
        #pragma unroll
        for (int r = 0; r < 16; ++r) acc[r] = 0.f;
        #pragma unroll
        for (int m = 0; m < 4; ++m) acc = __builtin_amdgcn_mfma_f32_32x32x16_f16(kf[m], qf[m], acc, 0, 0, 0);
        #pragma unroll
        for (int r = 0; r < 16; ++r) ssum += __builtin_amdgcn_exp2f(acc[r] * cexp);
        if (c + 1 < NCHUNK) {
            #pragma unroll
            for (int m = 0; m < 4; ++m) {
                f16x8 f;
                #pragma unroll
                for (int j = 0; j < 4; ++j) { f[j] = (_Float16)ra[m][j]; f[j+4] = (_Float16)rb[m][j]; }
                kf[m] = f;
            }
        }
    }
    ssum += __shfl_xor(ssum, 32);      // lanes l, l^32 hold complementary k-halves
    const float inv = 1.f / ssum;

    // ================= Pass 2: QK^T -> normalize -> attn stores + PV =================
    {
        const float* kp = kh + (size_t)qr * DH + hi * 8;
        #pragma unroll
        for (int m = 0; m < 4; ++m) { ra[m] = *(const f32x4*)(kp + m*16); rb[m] = *(const f32x4*)(kp + m*16 + 4); }
        #pragma unroll
        for (int m = 0; m < 4; ++m) {
            f16x8 f;
            #pragma unroll
            for (int j = 0; j < 4; ++j) { f[j] = (_Float16)ra[m][j]; f[j+4] = (_Float16)rb[m][j]; }
            kf[m] = f;
        }
    }
    f32x16 oacc0, oacc1;
    #pragma unroll
    for (int r = 0; r < 16; ++r) { oacc0[r] = 0.f; oacc1[r] = 0.f; }

    float vra[16], vrb[16];

    for (int c = 0; c < NCHUNK; ++c) {
        // V chunk (current): per-lane column reads, coalesced 128B per half-wave
        {
            const float* vp = vh + (size_t)(c*CH + hi*8) * DH + qr;
            #pragma unroll
            for (int u = 0; u < 2; ++u)
                #pragma unroll
                for (int j = 0; j < 8; ++j) {
                    vra[u*8+j] = vp[(u*16 + j) * DH];
                    vrb[u*8+j] = vp[(u*16 + j) * DH + 32];
                }
        }
        if (c + 1 < NCHUNK) {   // prefetch next K chunk
            const float* kp = kh + (size_t)((c+1)*CH + qr) * DH + hi * 8;
            #pragma unroll
            for (int m = 0; m < 4; ++m) { ra[m] = *(const f32x4*)(kp + m*16); rb[m] = *(const f32x4*)(kp + m*16 + 4); }
        }
        // QK^T
        f32x16 acc;
        #pragma unroll
        for (int r = 0; r < 16; ++r) acc[r] = 0.f;
        #pragma unroll
        for (int m = 0; m < 4; ++m) acc = __builtin_amdgcn_mfma_f32_32x32x16_f16(kf[m], qf[m], acc, 0, 0, 0);
        // normalized P; lane holds q-row qr, k(r) = (r&3) + 8*(r>>2) + 4*hi (+32c)
        float pn[16];
        #pragma unroll
        for (int r = 0; r < 16; ++r) pn[r] = __builtin_amdgcn_exp2f(acc[r] * cexp) * inv;
        // stage P into wave-private LDS (b128 writes, XOR granule swizzle)
        #pragma unroll
        for (int g = 0; g < 4; ++g) {
            f32x4 st; st[0]=pn[4*g]; st[1]=pn[4*g+1]; st[2]=pn[4*g+2]; st[3]=pn[4*g+3];
            const int slot = (2*g + hi) ^ (qr & 7);
            *(f32x4*)&ps[qr*CH + slot*4] = st;
        }
        // pack P -> fp16 A-fragments (cross-half exchange, verified in round 2)
        unsigned wd[8], pw[8];
        #pragma unroll
        for (int i = 0; i < 8; ++i) wd[i] = pk2(pn[2*i], pn[2*i+1]);
        #pragma unroll
        for (int i = 0; i < 8; ++i) pw[i] = __shfl_xor(wd[i], 32);
        // V B-fragments (col=lane&31=d, k = 16u + 8hi + j)
        f16x8 vf0[2], vf1[2];
        #pragma unroll
        for (int u = 0; u < 2; ++u) {
            f16x8 f0, f1;
            #pragma unroll
            for (int j = 0; j < 8; ++j) { f0[j] = (_Float16)vra[u*8+j]; f1[j] = (_Float16)vrb[u*8+j]; }
            vf0[u] = f0; vf1[u] = f1;
        }
        // PV MFMA
        #pragma unroll
        for (int u = 0; u < 2; ++u) {
            union { unsigned u4[4]; f16x8 v; } af;
            af.u4[0] = hi ? pw[4*u+2] : wd[4*u+0];
            af.u4[1] = hi ? pw[4*u+3] : wd[4*u+1];
            af.u4[2] = hi ? wd[4*u+2] : pw[4*u+0];
            af.u4[3] = hi ? wd[4*u+3] : pw[4*u+1];
            oacc0 = __builtin_amdgcn_mfma_f32_32x32x16_f16(af.v, vf0[u], oacc0, 0, 0, 0);
            oacc1 = __builtin_amdgcn_mfma_f32_32x32x16_f16(af.v, vf1[u], oacc1, 0, 0, 0);
        }
        // drain pstage -> full-line nontemporal attn stores (8 rows x 128B per instr)
        #pragma unroll
        for (int j2 = 0; j2 < 4; ++j2) {
            const int R  = j2*8 + (l >> 3);
            const int gr = l & 7;
            f32x4 t = *(const f32x4*)&ps[R*CH + ((gr ^ (R & 7)) * 4)];
            __builtin_nontemporal_store(t, (f32x4*)&attnh[(size_t)(q0 + R) * S_LEN + c*CH + gr*4]);
        }
        // convert next K chunk (vmcnt wait lands here, covered by the whole chunk)
        if (c + 1 < NCHUNK) {
            #pragma unroll
            for (int m = 0; m < 4; ++m) {
                f16x8 f;
                #pragma unroll
                for (int j = 0; j < 4; ++j) { f[j] = (_Float16)ra[m][j]; f[j+4] = (_Float16)rb[m][j]; }
                kf[m] = f;
            }
        }
    }

    // ================= Epilogue: O (A was normalized -> already normalized) =================
    #pragma unroll
    for (int r = 0; r < 16; ++r) {
        const int qrow = (r & 3) + 8*(r >> 2) + 4*hi;
        __builtin_nontemporal_store(oacc0[r], &outh[(size_t)(q0 + qrow) * DH + qr]);
        __builtin_nontemporal_store(oacc1[r], &outh[(size_t)(q0 + qrow) * DH + 32 + qr]);
    }
}

extern "C" void kernel_launch(void* const* d_in, const int* in_sizes, int n_in,
                              void* d_out, int out_size, void* d_ws, size_t ws_size,
                              hipStream_t stream) {
    const float* q = (const float*)d_in[0];
    const float* k = (const float*)d_in[1];
    const float* v = (const float*)d_in[2];
    float* out = (float*)d_out;
    attn_fused<<<dim3(512), dim3(256), 0, stream>>>(q, k, v, out);
}

// Round 5
// 411.781 us; speedup vs baseline: 1.4027x; 1.1296x over previous
//
#include <hip/hip_runtime.h>

#define S_LEN  1024
#define DH     64
#define CH     32                  // kv rows per chunk
#define HALF_K 512                 // k-range per wave (split-k x2)
#define NCHW   (HALF_K / CH)       // 16 chunks per wave
#define OUT_ELEMS (4 * 16 * 1024 * 64)

typedef _Float16 f16x8  __attribute__((ext_vector_type(8)));
typedef float    f32x4  __attribute__((ext_vector_type(4)));
typedef float    f32x16 __attribute__((ext_vector_type(16)));

static __device__ __forceinline__ unsigned pk2(float a, float b) {
    union { _Float16 h[2]; unsigned u; } x;
    x.h[0] = (_Float16)a; x.h[1] = (_Float16)b; return x.u;
}

static __device__ __forceinline__ f16x8 cvt8(f32x4 a, f32x4 b) {
    f16x8 f;
    #pragma unroll
    for (int j = 0; j < 4; ++j) { f[j] = (_Float16)a[j]; f[j+4] = (_Float16)b[j]; }
    return f;
}

__global__ __launch_bounds__(256, 4)
void attn_fused(const float* __restrict__ qg, const float* __restrict__ kg,
                const float* __restrict__ vg, float* __restrict__ dout)
{
    // 1024 blocks = 64 heads x 16 q-blocks(64 rows). bid%8 == head%8 -> head-XCD affinity.
    // Block = 4 waves: (qs = w&1) q-strip of 32 rows, (k2 = w>>1) k-half of 512.
    const int bid = blockIdx.x;
    const int h   = bid & 63;
    const int qb  = bid >> 6;          // 0..15
    const int tid = threadIdx.x;
    const int w   = tid >> 6;
    const int l   = tid & 63;
    const int qs  = w & 1;
    const int k2  = w >> 1;
    const int qr  = l & 31;            // q-row within strip / B-col / d-col
    const int hi  = l >> 5;
    const int q0  = qb * 64 + qs * 32;
    const int kb  = k2 * HALF_K;

    const float* __restrict__ qh = qg + (size_t)h * S_LEN * DH;
    const float* __restrict__ kh = kg + (size_t)h * S_LEN * DH;
    const float* __restrict__ vh = vg + (size_t)h * S_LEN * DH;
    float* __restrict__ outh  = dout + (size_t)h * S_LEN * DH;
    float* __restrict__ attnh = dout + (size_t)OUT_ELEMS + (size_t)h * S_LEN * S_LEN;

    __shared__ float pstage[4][CH * CH];     // 16 KB: per-wave P transpose; reused for O-reduce
    __shared__ float ssum_lds[2][2][CH];     // row-sum halves
    float* ps = pstage[w];

    const float cexp = 0.18033688011112042f;   // log2(e)/8 — softmax scale fused into exp2

    // ---- Q B-fragments (col=lane&31=q-row, k = 16m + 8hi + j)
    f16x8 qf[4];
    {
        const float* qrow = qh + (size_t)(q0 + qr) * DH + hi * 8;
        #pragma unroll
        for (int m = 0; m < 4; ++m)
            qf[m] = cvt8(*(const f32x4*)(qrow + m*16), *(const f32x4*)(qrow + m*16 + 4));
    }

    auto loadK = [&](f32x4* A, f32x4* B, int c) {
        const float* kp = kh + (size_t)(kb + c*CH + qr) * DH + hi * 8;
        #pragma unroll
        for (int m = 0; m < 4; ++m) { A[m] = *(const f32x4*)(kp + m*16); B[m] = *(const f32x4*)(kp + m*16 + 4); }
    };

    // ================= Pass 1: QK^T -> partial row sums (double-buffered) =================
    float ssum = 0.f;
    {
        f32x4 a0[4], b0[4], a1[4], b1[4];
        auto qkexp = [&](const f32x4* A, const f32x4* B) {
            f32x16 acc;
            #pragma unroll
            for (int r = 0; r < 16; ++r) acc[r] = 0.f;
            #pragma unroll
            for (int m = 0; m < 4; ++m)
                acc = __builtin_amdgcn_mfma_f32_32x32x16_f16(cvt8(A[m], B[m]), qf[m], acc, 0, 0, 0);
            #pragma unroll
            for (int r = 0; r < 16; ++r) ssum += __builtin_amdgcn_exp2f(acc[r] * cexp);
        };
        loadK(a0, b0, 0);
        for (int cc = 0; cc < NCHW; cc += 2) {
            if (cc + 1 < NCHW) loadK(a1, b1, cc + 1);
            qkexp(a0, b0);
            if (cc + 2 < NCHW) loadK(a0, b0, cc + 2);
            if (cc + 1 < NCHW) qkexp(a1, b1);
        }
    }
    ssum += __shfl_xor(ssum, 32);      // lanes l, l^32 hold complementary k-quarters of this half
    if (hi == 0) ssum_lds[qs][k2][qr] = ssum;
    __syncthreads();
    const float inv = 1.f / (ssum_lds[qs][0][qr] + ssum_lds[qs][1][qr]);

    // ================= Pass 2: QK^T -> normalize -> attn stores + PV =================
    f32x16 oacc0, oacc1;
    #pragma unroll
    for (int r = 0; r < 16; ++r) { oacc0[r] = 0.f; oacc1[r] = 0.f; }

    f32x4 ka[4], kbf[4];
    float vra[16], vrb[16];
    loadK(ka, kbf, 0);

    for (int c = 0; c < NCHW; ++c) {
        // V chunk (current): per-lane column reads (coalesced 128B per half-wave), used late
        {
            const float* vp = vh + (size_t)(kb + c*CH + hi*8) * DH + qr;
            #pragma unroll
            for (int u = 0; u < 2; ++u)
                #pragma unroll
                for (int j = 0; j < 8; ++j) {
                    vra[u*8+j] = vp[(u*16 + j) * DH];
                    vrb[u*8+j] = vp[(u*16 + j) * DH + 32];
                }
        }
        // QK^T (convert K fragments on demand — no persistent kf)
        f32x16 acc;
        #pragma unroll
        for (int r = 0; r < 16; ++r) acc[r] = 0.f;
        #pragma unroll
        for (int m = 0; m < 4; ++m)
            acc = __builtin_amdgcn_mfma_f32_32x32x16_f16(cvt8(ka[m], kbf[m]), qf[m], acc, 0, 0, 0);
        // prefetch next K chunk; fill window = exp+pack+PV+stores below
        if (c + 1 < NCHW) loadK(ka, kbf, c + 1);
        // normalized P; lane holds q-row qr, k(r) = (r&3) + 8*(r>>2) + 4*hi
        float pn[16];
        #pragma unroll
        for (int r = 0; r < 16; ++r) pn[r] = __builtin_amdgcn_exp2f(acc[r] * cexp) * inv;
        // stage P into wave-private LDS (b128 writes, XOR granule swizzle)
        #pragma unroll
        for (int g = 0; g < 4; ++g) {
            f32x4 st; st[0]=pn[4*g]; st[1]=pn[4*g+1]; st[2]=pn[4*g+2]; st[3]=pn[4*g+3];
            const int slot = (2*g + hi) ^ (qr & 7);
            *(f32x4*)&ps[qr*CH + slot*4] = st;
        }
        // pack P -> fp16 A-fragments (cross-half exchange, verified rounds 2/4)
        unsigned wd[8], pw[8];
        #pragma unroll
        for (int i = 0; i < 8; ++i) wd[i] = pk2(pn[2*i], pn[2*i+1]);
        #pragma unroll
        for (int i = 0; i < 8; ++i) pw[i] = __shfl_xor(wd[i], 32);
        // PV MFMA (V converted here — loads have had the whole QK/exp phase to land)
        #pragma unroll
        for (int u = 0; u < 2; ++u) {
            f16x8 f0, f1;
            #pragma unroll
            for (int j = 0; j < 8; ++j) { f0[j] = (_Float16)vra[u*8+j]; f1[j] = (_Float16)vrb[u*8+j]; }
            union { unsigned u4[4]; f16x8 v; } af;
            af.u4[0] = hi ? pw[4*u+2] : wd[4*u+0];
            af.u4[1] = hi ? pw[4*u+3] : wd[4*u+1];
            af.u4[2] = hi ? wd[4*u+2] : pw[4*u+0];
            af.u4[3] = hi ? wd[4*u+3] : pw[4*u+1];
            oacc0 = __builtin_amdgcn_mfma_f32_32x32x16_f16(af.v, f0, oacc0, 0, 0, 0);
            oacc1 = __builtin_amdgcn_mfma_f32_32x32x16_f16(af.v, f1, oacc1, 0, 0, 0);
        }
        // drain pstage -> full-line nontemporal attn stores (8 rows x 128B per instr)
        #pragma unroll
        for (int j2 = 0; j2 < 4; ++j2) {
            const int R  = j2*8 + (l >> 3);
            const int gr = l & 7;
            f32x4 t = *(const f32x4*)&ps[R*CH + ((gr ^ (R & 7)) * 4)];
            __builtin_nontemporal_store(t, (f32x4*)&attnh[(size_t)(q0 + R) * S_LEN + kb + c*CH + gr*4]);
        }
    }

    // ================= O reduction across k-halves (reuse pstage LDS) =================
    __syncthreads();                       // all pstage drains done
    float* red = &pstage[0][0];            // 4096 floats: [qs][r 0..31][lane]
    if (k2 == 1) {
        #pragma unroll
        for (int r = 0; r < 16; ++r) {
            red[qs*2048 + r*64 + l]        = oacc0[r];
            red[qs*2048 + (16 + r)*64 + l] = oacc1[r];
        }
    }
    __syncthreads();
    if (k2 == 0) {
        #pragma unroll
        for (int r = 0; r < 16; ++r) {
            oacc0[r] += red[qs*2048 + r*64 + l];
            oacc1[r] += red[qs*2048 + (16 + r)*64 + l];
        }
        #pragma unroll
        for (int r = 0; r < 16; ++r) {
            const int qrow = (r & 3) + 8*(r >> 2) + 4*hi;
            __builtin_nontemporal_store(oacc0[r], &outh[(size_t)(q0 + qrow) * DH + qr]);
            __builtin_nontemporal_store(oacc1[r], &outh[(size_t)(q0 + qrow) * DH + 32 + qr]);
        }
    }
}

extern "C" void kernel_launch(void* const* d_in, const int* in_sizes, int n_in,
                              void* d_out, int out_size, void* d_ws, size_t ws_size,
                              hipStream_t stream) {
    const float* q = (const float*)d_in[0];
    const float* k = (const float*)d_in[1];
    const float* v = (const float*)d_in[2];
    float* out = (float*)d_out;
    attn_fused<<<dim3(1024), dim3(256), 0, stream>>>(q, k, v, out);
}